// Round 1
// baseline (338.784 us; speedup 1.0000x reference)
//
#include <hip/hip_runtime.h>
#include <hip/hip_bf16.h>
#include <stdint.h>

#define DEVINL __device__ __forceinline__

typedef unsigned short u16;
typedef unsigned int u32;
typedef __attribute__((ext_vector_type(8))) __bf16 bf16x8;
typedef __attribute__((ext_vector_type(4))) float f32x4;

static constexpr int NQ = 2048, MC = 512, DIMC = 1024, LTOT = 2560;
static constexpr float EPS = 1e-6f;

DEVINL u16 f2bf(float f) {
  u32 u = __float_as_uint(f);
  u32 r = (u + 0x7FFFu + ((u >> 16) & 1u)) >> 16;
  return (u16)r;
}
DEVINL float bf2f(u16 h) { return __uint_as_float(((u32)h) << 16); }

DEVINL void gload16(const void* g, void* l) {
  __builtin_amdgcn_global_load_lds((const __attribute__((address_space(1))) void*)g,
                                   (__attribute__((address_space(3))) void*)l, 16, 0, 0);
}

// ---------------- fp32 -> bf16 convert ----------------
__global__ void cvt_bf16(const float* __restrict__ src, u16* __restrict__ dst) {
  size_t i = ((size_t)blockIdx.x * 256 + threadIdx.x) * 8;
  float4 a = *(const float4*)(src + i);
  float4 b = *(const float4*)(src + i + 4);
  union { uint4 u; u16 s[8]; } o;
  o.s[0] = f2bf(a.x); o.s[1] = f2bf(a.y); o.s[2] = f2bf(a.z); o.s[3] = f2bf(a.w);
  o.s[4] = f2bf(b.x); o.s[5] = f2bf(b.y); o.s[6] = f2bf(b.z); o.s[7] = f2bf(b.w);
  *(uint4*)(dst + i) = o.u;
}

// ---------------- C = A @ B^T  (A:[M,K] bf16, B:[N,K] bf16) ----------------
template <int M, int N, int K, bool OUT_BF16, bool HAS_BIAS>
__launch_bounds__(256, 2)
__global__ void gemm_bt(const u16* __restrict__ A, const u16* __restrict__ Bw,
                        void* __restrict__ Cout, const float* __restrict__ bias) {
  __shared__ u16 la[128 * 64];
  __shared__ u16 lb[128 * 64];
  const int tid = threadIdx.x;
  const int lane = tid & 63, wid = tid >> 6;
  const int tm = blockIdx.x / (N / 128), tn = blockIdx.x % (N / 128);
  const int m0 = tm * 128, n0 = tn * 128;
  const int wm = (wid >> 1) * 64, wn = (wid & 1) * 64;
  const int srow = lane >> 3, scol = (lane & 7) * 8;
  const int cn = lane & 15, rg = lane >> 4;

  f32x4 acc[4][4] = {};

  for (int kt = 0; kt < K; kt += 64) {
    __syncthreads();
#pragma unroll
    for (int c = 0; c < 4; ++c) {
      int s = c * 4 + wid;
      gload16(A + (size_t)(m0 + s * 8 + srow) * K + kt + scol, &la[s * 512]);
      gload16(Bw + (size_t)(n0 + s * 8 + srow) * K + kt + scol, &lb[s * 512]);
    }
    __syncthreads();
#pragma unroll
    for (int kk = 0; kk < 2; ++kk) {
      bf16x8 af[4], bfr[4];
      const int ko = kk * 32 + rg * 8;
#pragma unroll
      for (int mi = 0; mi < 4; ++mi) af[mi] = *(const bf16x8*)&la[(wm + mi * 16 + cn) * 64 + ko];
#pragma unroll
      for (int ni = 0; ni < 4; ++ni) bfr[ni] = *(const bf16x8*)&lb[(wn + ni * 16 + cn) * 64 + ko];
#pragma unroll
      for (int mi = 0; mi < 4; ++mi)
#pragma unroll
        for (int ni = 0; ni < 4; ++ni)
          acc[mi][ni] = __builtin_amdgcn_mfma_f32_16x16x32_bf16(af[mi], bfr[ni], acc[mi][ni], 0, 0, 0);
    }
  }
#pragma unroll
  for (int mi = 0; mi < 4; ++mi)
#pragma unroll
    for (int ni = 0; ni < 4; ++ni) {
      const int col = n0 + wn + ni * 16 + cn;
      const float bv = HAS_BIAS ? bias[col] : 0.0f;
#pragma unroll
      for (int r = 0; r < 4; ++r) {
        const int row = m0 + wm + mi * 16 + rg * 4 + r;
        const float v = acc[mi][ni][r] + bv;
        if (OUT_BF16) ((u16*)Cout)[(size_t)row * N + col] = f2bf(v);
        else          ((float*)Cout)[(size_t)row * N + col] = v;
      }
    }
}

// ---------------- K rmsnorm + V transpose into attention layouts ----------------
// qkvx: [4096, 3072] bf16 (q|k|v per head), kvy: [1024, 2048] bf16 (k|v per head)
// kb : [B*H, 2560, 64] bf16 normalized keys (x rows 0..2047, y rows 2048..2559)
// vtb: [B*H, 64, 2560] bf16 transposed values
__global__ void reorg_kv(const u16* __restrict__ qkvx, const u16* __restrict__ kvy,
                         const float* __restrict__ knw,
                         u16* __restrict__ kb, u16* __restrict__ vtb) {
  const int tid = threadIdx.x;
  const int bh = blockIdx.x / 40, t = blockIdx.x % 40;
  const int b = bh >> 4, h = bh & 15;
  const u16* src; int stride, kcol, vcol, l0, srow0;
  if (t < 32) {
    src = qkvx; stride = 3 * DIMC; kcol = DIMC + h * 64; vcol = 2 * DIMC + h * 64;
    srow0 = b * NQ + t * 64; l0 = t * 64;
  } else {
    src = kvy; stride = 2 * DIMC; kcol = h * 64; vcol = DIMC + h * 64;
    srow0 = b * MC + (t - 32) * 64; l0 = NQ + (t - 32) * 64;
  }
  {  // K with rmsnorm: thread -> token i, 16 dims
    const int i = tid >> 2, d0 = (tid & 3) * 16;
    const u16* p = src + (size_t)(srow0 + i) * stride + kcol + d0;
    uint4 r0 = *(const uint4*)(p);
    uint4 r1 = *(const uint4*)(p + 8);
    const u16* s0 = (const u16*)&r0; const u16* s1 = (const u16*)&r1;
    float f[16]; float ss = 0.f;
#pragma unroll
    for (int j = 0; j < 8; ++j) { f[j] = bf2f(s0[j]); ss += f[j] * f[j]; }
#pragma unroll
    for (int j = 0; j < 8; ++j) { f[8 + j] = bf2f(s1[j]); ss += f[8 + j] * f[8 + j]; }
    ss += __shfl_xor(ss, 1); ss += __shfl_xor(ss, 2);
    const float rs = rsqrtf(ss * (1.0f / 64.0f) + EPS);
    union { uint4 u; u16 s[8]; } o0, o1;
#pragma unroll
    for (int j = 0; j < 8; ++j) o0.s[j] = f2bf(f[j] * rs * knw[d0 + j]);
#pragma unroll
    for (int j = 0; j < 8; ++j) o1.s[j] = f2bf(f[8 + j] * rs * knw[d0 + 8 + j]);
    u16* q = kb + ((size_t)bh * LTOT + l0 + i) * 64 + d0;
    *(uint4*)q = o0.u;
    *(uint4*)(q + 8) = o1.u;
  }
  {  // V transpose: thread -> dim d, 16 tokens
    const int d = tid >> 2, g = tid & 3;
    const u16* p = src + (size_t)srow0 * stride + vcol + d;
    u16 buf[16];
#pragma unroll
    for (int j = 0; j < 16; ++j) buf[j] = p[(size_t)(g * 16 + j) * stride];
    u16* q = vtb + ((size_t)bh * 64 + d) * LTOT + l0 + g * 16;
    *(uint4*)q = *(uint4*)&buf[0];
    *(uint4*)(q + 8) = *(uint4*)&buf[8];
  }
}

// ---------------- flash attention ----------------
// grid: (B*H) * 32 q-tiles, 256 threads. BQ=64 (16 rows/wave), BK=64, D=64.
__launch_bounds__(256, 2)
__global__ void attn_fwd(const u16* __restrict__ qkvx, const u16* __restrict__ kb,
                         const u16* __restrict__ vtb, const float* __restrict__ qnw,
                         u16* __restrict__ attnb) {
  __shared__ u16 lk[64 * 72];
  __shared__ u16 lv[64 * 72];
  __shared__ u16 lp[4 * 16 * 72];
  const int tid = threadIdx.x;
  const int lane = tid & 63, wid = tid >> 6;
  const int qt = blockIdx.x & 31, bh = blockIdx.x >> 5;
  const int b = bh >> 4, h = bh & 15;
  const int cn = lane & 15, rg = lane >> 4;
  const int dbase = rg * 8;

  // Q load + rmsnorm; fold softmax scale (1/8) and log2e into q
  bf16x8 qa[2];
  {
    const u16* qp = qkvx + (size_t)(b * NQ + qt * 64 + wid * 16 + cn) * (3 * DIMC) + h * 64;
    uint4 q0 = *(const uint4*)(qp + dbase);
    uint4 q1 = *(const uint4*)(qp + 32 + dbase);
    const u16* s0 = (const u16*)&q0; const u16* s1 = (const u16*)&q1;
    float f[16]; float ss = 0.f;
#pragma unroll
    for (int j = 0; j < 8; ++j) { f[j] = bf2f(s0[j]); ss += f[j] * f[j]; }
#pragma unroll
    for (int j = 0; j < 8; ++j) { f[8 + j] = bf2f(s1[j]); ss += f[8 + j] * f[8 + j]; }
    ss += __shfl_xor(ss, 16); ss += __shfl_xor(ss, 32);
    const float rs = rsqrtf(ss * (1.0f / 64.0f) + EPS) * 0.125f * 1.44269504088896f;
    union { bf16x8 v; u16 s[8]; } o0, o1;
#pragma unroll
    for (int j = 0; j < 8; ++j) o0.s[j] = f2bf(f[j] * rs * qnw[dbase + j]);
#pragma unroll
    for (int j = 0; j < 8; ++j) o1.s[j] = f2bf(f[8 + j] * rs * qnw[32 + dbase + j]);
    qa[0] = o0.v; qa[1] = o1.v;
  }

  const u16* kb_bh = kb + (size_t)bh * LTOT * 64;
  const u16* vt_bh = vtb + (size_t)bh * 64 * LTOT;
  const int row_s = tid >> 3, cc8 = (tid & 7) * 8;

  uint4 rk0, rk1, rv0, rv1;
  auto loadtile = [&](int l0) {
    rk0 = *(const uint4*)(kb_bh + (size_t)(l0 + row_s) * 64 + cc8);
    rk1 = *(const uint4*)(kb_bh + (size_t)(l0 + row_s + 32) * 64 + cc8);
    rv0 = *(const uint4*)(vt_bh + (size_t)row_s * LTOT + l0 + cc8);
    rv1 = *(const uint4*)(vt_bh + (size_t)(row_s + 32) * LTOT + l0 + cc8);
  };
  loadtile(0);

  float m_run[4], l_run[4];
  f32x4 o[4] = {};
#pragma unroll
  for (int r = 0; r < 4; ++r) { m_run[r] = -3.0e38f; l_run[r] = 0.f; }

  for (int t = 0; t < LTOT / 64; ++t) {
    __syncthreads();
    *(uint4*)&lk[row_s * 72 + cc8] = rk0;
    *(uint4*)&lk[(row_s + 32) * 72 + cc8] = rk1;
    *(uint4*)&lv[row_s * 72 + cc8] = rv0;
    *(uint4*)&lv[(row_s + 32) * 72 + cc8] = rv1;
    __syncthreads();
    if (t + 1 < LTOT / 64) loadtile((t + 1) * 64);

    // S = Q @ K^T (per-wave 16 q-rows x 64 keys)
    f32x4 s[4];
#pragma unroll
    for (int ki = 0; ki < 4; ++ki) {
      bf16x8 k0 = *(const bf16x8*)&lk[(ki * 16 + cn) * 72 + dbase];
      bf16x8 k1 = *(const bf16x8*)&lk[(ki * 16 + cn) * 72 + 32 + dbase];
      f32x4 z = {0.f, 0.f, 0.f, 0.f};
      z = __builtin_amdgcn_mfma_f32_16x16x32_bf16(qa[0], k0, z, 0, 0, 0);
      s[ki] = __builtin_amdgcn_mfma_f32_16x16x32_bf16(qa[1], k1, z, 0, 0, 0);
    }
    // online softmax (s already in log2 units)
    float mx[4];
#pragma unroll
    for (int r = 0; r < 4; ++r) mx[r] = fmaxf(fmaxf(s[0][r], s[1][r]), fmaxf(s[2][r], s[3][r]));
#pragma unroll
    for (int msk = 1; msk <= 8; msk <<= 1)
#pragma unroll
      for (int r = 0; r < 4; ++r) mx[r] = fmaxf(mx[r], __shfl_xor(mx[r], msk));
    float corr[4];
#pragma unroll
    for (int r = 0; r < 4; ++r) {
      const float mn = fmaxf(m_run[r], mx[r]);
      corr[r] = exp2f(m_run[r] - mn);
      m_run[r] = mn;
    }
    float p[4][4], rsum[4];
#pragma unroll
    for (int r = 0; r < 4; ++r) rsum[r] = 0.f;
#pragma unroll
    for (int ki = 0; ki < 4; ++ki)
#pragma unroll
      for (int r = 0; r < 4; ++r) { p[ki][r] = exp2f(s[ki][r] - m_run[r]); rsum[r] += p[ki][r]; }
#pragma unroll
    for (int msk = 1; msk <= 8; msk <<= 1)
#pragma unroll
      for (int r = 0; r < 4; ++r) rsum[r] += __shfl_xor(rsum[r], msk);
#pragma unroll
    for (int r = 0; r < 4; ++r) l_run[r] = l_run[r] * corr[r] + rsum[r];
#pragma unroll
    for (int ni = 0; ni < 4; ++ni)
#pragma unroll
      for (int r = 0; r < 4; ++r) o[ni][r] *= corr[r];

    // P through per-wave LDS to reach MFMA A-layout
    u16* lpw = &lp[wid * 16 * 72];
#pragma unroll
    for (int ki = 0; ki < 4; ++ki)
#pragma unroll
      for (int r = 0; r < 4; ++r)
        lpw[(rg * 4 + r) * 72 + ki * 16 + cn] = f2bf(p[ki][r]);
    bf16x8 pa0 = *(const bf16x8*)&lpw[cn * 72 + dbase];
    bf16x8 pa1 = *(const bf16x8*)&lpw[cn * 72 + 32 + dbase];

    // O += P @ V
#pragma unroll
    for (int ni = 0; ni < 4; ++ni) {
      bf16x8 v0 = *(const bf16x8*)&lv[(ni * 16 + cn) * 72 + dbase];
      bf16x8 v1 = *(const bf16x8*)&lv[(ni * 16 + cn) * 72 + 32 + dbase];
      o[ni] = __builtin_amdgcn_mfma_f32_16x16x32_bf16(pa0, v0, o[ni], 0, 0, 0);
      o[ni] = __builtin_amdgcn_mfma_f32_16x16x32_bf16(pa1, v1, o[ni], 0, 0, 0);
    }
  }
  const int qrow0 = qt * 64 + wid * 16 + rg * 4;
#pragma unroll
  for (int ni = 0; ni < 4; ++ni)
#pragma unroll
    for (int r = 0; r < 4; ++r) {
      const float v = o[ni][r] / l_run[r];
      attnb[(size_t)(b * NQ + qrow0 + r) * DIMC + h * 64 + ni * 16 + cn] = f2bf(v);
    }
}

extern "C" void kernel_launch(void* const* d_in, const int* in_sizes, int n_in,
                              void* d_out, int out_size, void* d_ws, size_t ws_size,
                              hipStream_t stream) {
  const float* x      = (const float*)d_in[0];
  const float* ctx    = (const float*)d_in[1];
  const float* qkv_w  = (const float*)d_in[2];
  const float* kv_y_w = (const float*)d_in[3];
  const float* proj_w = (const float*)d_in[4];
  const float* proj_b = (const float*)d_in[5];
  const float* q_norm_w = (const float*)d_in[6];
  const float* k_norm_w = (const float*)d_in[7];
  float* out = (float*)d_out;

  char* ws = (char*)d_ws;
  u16* xb    = (u16*)(ws);                // 4096*1024      (8.0 MB)
  u16* cb    = (u16*)(ws + 8388608);      // 1024*1024      (2.0 MB)
  u16* wqkv  = (u16*)(ws + 10485760);     // 3072*1024      (6.0 MB)
  u16* wkv   = (u16*)(ws + 16777216);     // 2048*1024      (4.0 MB)
  u16* wproj = (u16*)(ws + 20971520);     // 1024*1024      (2.0 MB)
  u16* qkvx  = (u16*)(ws + 23068672);     // 4096*3072      (24 MB)
  u16* kvy   = (u16*)(ws + 48234496);     // 1024*2048      (4.0 MB)
  u16* kbuf  = (u16*)(ws + 52428800);     // 32*2560*64     (10 MB)
  u16* vtb   = (u16*)(ws + 62914560);     // 32*64*2560     (10 MB)
  u16* attnb = (u16*)(ws + 73400320);     // 4096*1024      (8.0 MB)

  cvt_bf16<<<2048, 256, 0, stream>>>(x, xb);
  cvt_bf16<<<512, 256, 0, stream>>>(ctx, cb);
  cvt_bf16<<<1536, 256, 0, stream>>>(qkv_w, wqkv);
  cvt_bf16<<<1024, 256, 0, stream>>>(kv_y_w, wkv);
  cvt_bf16<<<512, 256, 0, stream>>>(proj_w, wproj);

  gemm_bt<4096, 3072, 1024, true, false><<<32 * 24, 256, 0, stream>>>(xb, wqkv, qkvx, nullptr);
  gemm_bt<1024, 2048, 1024, true, false><<<8 * 16, 256, 0, stream>>>(cb, wkv, kvy, nullptr);
  reorg_kv<<<32 * 40, 256, 0, stream>>>(qkvx, kvy, k_norm_w, kbuf, vtb);
  attn_fwd<<<32 * 32, 256, 0, stream>>>(qkvx, kbuf, vtb, q_norm_w, attnb);
  gemm_bt<4096, 1024, 1024, false, true><<<32 * 8, 256, 0, stream>>>(attnb, wproj, out, proj_b);
}